// Round 8
// baseline (198.282 us; speedup 1.0000x reference)
//
#include <hip/hip_runtime.h>
#include <hip/hip_bf16.h>

#define D_ 128
#define S_ 512
#define B_ 4
#define H_ 8

typedef short bf16x8 __attribute__((ext_vector_type(8)));
typedef float f32x4 __attribute__((ext_vector_type(4)));
typedef float f32x2 __attribute__((ext_vector_type(2)));

__device__ __forceinline__ short f2bf(float f) {
  __hip_bfloat16 h = __float2bfloat16(f);
  return __builtin_bit_cast(short, h);
}
__device__ __forceinline__ float bf2f(short s) {
  unsigned u = ((unsigned)(unsigned short)s) << 16;
  return __builtin_bit_cast(float, u);
}
__device__ __forceinline__ float fsigmoid(float x) {
  return __builtin_amdgcn_rcpf(1.0f + __expf(-x));
}

// Proj PROBE: identical math to r4, inner work repeated 32x (idempotent).
// Purpose: dispatch dur ~32*Pk > 50us -> appears in rocprof top-5 with
// counters; Pk = dur/32.
__global__ __launch_bounds__(256)
void proj_kernel(const float* __restrict__ x, const float* __restrict__ w1,
                 const float* __restrict__ b1, float* __restrict__ Aq,
                 float* __restrict__ Cq) {
  __shared__ float xs[4 * D_];
  __shared__ f32x4 red[256][5];
  const int t = threadIdx.x;
  const int row0 = blockIdx.x * 4;
  ((float2*)xs)[t] = ((const float2*)(x + row0 * D_))[t];
  __syncthreads();
  const int combo = t & 63;
  const int e4 = (combo & 31) * 4;
  const int half = combo >> 5;
  const int kq = t >> 6;
  const float* w1p = w1 + (half * D_ + kq * 32) * D_ + e4;
  const float* xq = xs + kq * 32;

  #pragma unroll 1
  for (int rep = 0; rep < 32; ++rep) {
    f32x4 acc[4] = {};
    #pragma unroll 8
    for (int k = 0; k < 32; ++k) {
      float4 wv = *(const float4*)(w1p + k * D_);
      #pragma unroll
      for (int r = 0; r < 4; ++r) {
        float xv = xq[r * D_ + k];
        acc[r][0] += xv * wv.x; acc[r][1] += xv * wv.y;
        acc[r][2] += xv * wv.z; acc[r][3] += xv * wv.w;
      }
    }
    #pragma unroll
    for (int r = 0; r < 4; ++r) red[t][r] = acc[r];
    __syncthreads();
    const int r = t >> 6;
    const int c2 = t & 63;
    f32x4 s = red[c2][r];
    #pragma unroll
    for (int q = 1; q < 4; ++q) {
      f32x4 v = red[c2 + 64 * q][r];
      s[0] += v[0]; s[1] += v[1]; s[2] += v[2]; s[3] += v[3];
    }
    const int fe4 = (c2 & 31) * 4;
    const int row = row0 + r;
    if ((c2 >> 5) == 0) {
      float4 bv = *(const float4*)(b1 + fe4);
      s[0] += bv.x; s[1] += bv.y; s[2] += bv.z; s[3] += bv.w;
      *(f32x4*)(Aq + row * D_ + fe4) = s;
    } else {
      *(f32x4*)(Cq + row * D_ + fe4) = s;
    }
    __syncthreads();   // protect red[] before next rep overwrites
  }
}

// Edge PROBE: identical math to r4, j-loop repeated 6x (idempotent).
// Purpose: dispatch dur ~ S + 6L > 50us -> rocprof top-5 with counters;
// L ~= dur/6. Staging runs once (as in r4).
__global__ __launch_bounds__(512, 4)
void edge_kernel(const float* __restrict__ Aq, const float* __restrict__ Cq,
                 const float* __restrict__ w2, const float* __restrict__ b2,
                 float* __restrict__ out) {
  __shared__ short cbf[256 * D_];        // 64 KB
  const int t = threadIdx.x;
  const int lane = t & 63;
  const int wid = t >> 6;                // 0..7
  const int b  = blockIdx.x >> 7;
  const int jh = (blockIdx.x >> 6) & 1;  // j half
  const int ig = blockIdx.x & 63;
  const int i = ig * 8 + wid;

  {
    const float* cb = Cq + (b * S_ + jh * 256) * D_;
    #pragma unroll
    for (int it = 0; it < 8; ++it) {
      int p = t + it * 512;
      int row = p >> 4;
      int u = p & 15;
      const float* src = cb + row * D_ + u * 8;
      float4 v0 = *(const float4*)src;
      float4 v1 = *(const float4*)(src + 4);
      bf16x8 w;
      w[0] = f2bf(v0.x); w[1] = f2bf(v0.y); w[2] = f2bf(v0.z); w[3] = f2bf(v0.w);
      w[4] = f2bf(v1.x); w[5] = f2bf(v1.y); w[6] = f2bf(v1.z); w[7] = f2bf(v1.w);
      *(bf16x8*)(cbf + row * D_ + (u ^ (row & 7)) * 8) = w;
    }
  }

  const int jcol = lane & 15;
  const int lgrp = lane >> 4;
  const int sw = jcol & 7;

  f32x2 apk[4][4];
  {
    const float* Ai = Aq + (b * S_ + i) * D_ + lgrp * 8;
    #pragma unroll
    for (int ch = 0; ch < 4; ++ch) {
      float4 v0 = *(const float4*)(Ai + ch * 32);
      float4 v1 = *(const float4*)(Ai + ch * 32 + 4);
      apk[ch][0][0] = v0.x; apk[ch][0][1] = v0.y;
      apk[ch][1][0] = v0.z; apk[ch][1][1] = v0.w;
      apk[ch][2][0] = v1.x; apk[ch][2][1] = v1.y;
      apk[ch][3][0] = v1.z; apk[ch][3][1] = v1.w;
    }
  }
  bf16x8 w2f[4];
  #pragma unroll
  for (int ch = 0; ch < 4; ++ch) {
    #pragma unroll
    for (int e = 0; e < 8; ++e) {
      float wv = (jcol < H_) ? w2[(ch * 32 + lgrp * 8 + e) * H_ + jcol] : 0.0f;
      w2f[ch][e] = f2bf(wv);
    }
  }
  const float b2v = (jcol < H_) ? b2[jcol] : 0.0f;
  float* outp = out + (((size_t)(b * H_ + (jcol & 7)) * S_ + i) * S_)
                + jh * 256 + lgrp * 4;

  __syncthreads();

  bf16x8 cva[4], cvb[4];
  auto LOADT = [&](bf16x8 (&dst)[4], int jt) {
    const short* bp = cbf + (jt * 16 + jcol) * D_;
    #pragma unroll
    for (int ch = 0; ch < 4; ++ch)
      dst[ch] = *(const bf16x8*)(bp + (((ch * 4 + lgrp) ^ sw) * 8));
  };
  auto COMPUTE = [&](bf16x8 (&cv)[4], int jt) {
    f32x4 acc = {0.f, 0.f, 0.f, 0.f};
    #pragma unroll
    for (int ch = 0; ch < 4; ++ch) {
      bf16x8 hf;
      #pragma unroll
      for (int p = 0; p < 4; ++p) {
        f32x2 v;
        v[0] = bf2f(cv[ch][2 * p]);
        v[1] = bf2f(cv[ch][2 * p + 1]);
        v += apk[ch][p];
        hf[2 * p]     = f2bf(fmaxf(v[0], 0.f));
        hf[2 * p + 1] = f2bf(fmaxf(v[1], 0.f));
      }
      acc = __builtin_amdgcn_mfma_f32_16x16x32_bf16(hf, w2f[ch], acc, 0, 0, 0);
    }
    if (jcol < H_) {
      float4 o;
      o.x = fsigmoid(acc[0] + b2v);
      o.y = fsigmoid(acc[1] + b2v);
      o.z = fsigmoid(acc[2] + b2v);
      o.w = fsigmoid(acc[3] + b2v);
      *(float4*)(outp + jt * 16) = o;
    }
  };

  #pragma unroll 1
  for (int rep = 0; rep < 6; ++rep) {
    LOADT(cva, 0);
    #pragma unroll 1
    for (int jt = 0; jt < 16; jt += 2) {
      LOADT(cvb, jt + 1);
      COMPUTE(cva, jt);
      LOADT(cva, (jt + 2) & 15);
      COMPUTE(cvb, jt + 1);
    }
  }
}

extern "C" void kernel_launch(void* const* d_in, const int* in_sizes, int n_in,
                              void* d_out, int out_size, void* d_ws, size_t ws_size,
                              hipStream_t stream) {
  const float* x  = (const float*)d_in[0];
  const float* w1 = (const float*)d_in[1];
  const float* b1 = (const float*)d_in[2];
  const float* w2 = (const float*)d_in[3];
  const float* b2 = (const float*)d_in[4];
  float* out = (float*)d_out;
  float* Aq = (float*)d_ws;                 // 2048*128 f32 = 1 MB
  float* Cq = Aq + B_ * S_ * D_;            // +1 MB
  // PROBE round: single launch each, work repeated internally (x32 / x6)
  // so both dispatches exceed ~50us and surface in rocprof top-5 with
  // counters. Pk = proj_dur/32, L ~= edge_dur/6, OV = 26.37 - S - L.
  proj_kernel<<<(B_ * S_) / 4, 256, 0, stream>>>(x, w1, b1, Aq, Cq);
  edge_kernel<<<B_ * 2 * 64, 512, 0, stream>>>(Aq, Cq, w2, b2, out);
}

// Round 9
// 37.819 us; speedup vs baseline: 5.2429x; 5.2429x over previous
//
#include <hip/hip_runtime.h>
#include <hip/hip_bf16.h>

#define D_ 128
#define S_ 512
#define B_ 4
#define H_ 8

typedef short bf16x8 __attribute__((ext_vector_type(8)));
typedef unsigned int u32x4 __attribute__((ext_vector_type(4)));
typedef float f32x4 __attribute__((ext_vector_type(4)));
typedef float f32x2 __attribute__((ext_vector_type(2)));

__device__ __forceinline__ short f2bf(float f) {          // cold paths only
  __hip_bfloat16 h = __float2bfloat16(f);
  return __builtin_bit_cast(short, h);
}
__device__ __forceinline__ float fsigmoid(float x) {
  return __builtin_amdgcn_rcpf(1.0f + __expf(-x));
}
// HW packed f32->bf16 (RNE), 1 instr per 2 elements. No builtin on gfx950.
__device__ __forceinline__ unsigned int cvt_pk_bf16(float lo, float hi) {
  unsigned int r;
  asm("v_cvt_pk_bf16_f32 %0, %1, %2" : "=v"(r) : "v"(lo), "v"(hi));
  return r;
}

// Proj v2 (r4 version): A=x@w1[:D]+b1, C=x@w1[D:].
// 512 blocks x 256 thr, 4 rows/block, k-quarter split; w1 read once/block.
__global__ __launch_bounds__(256)
void proj_kernel(const float* __restrict__ x, const float* __restrict__ w1,
                 const float* __restrict__ b1, float* __restrict__ Aq,
                 float* __restrict__ Cq) {
  __shared__ float xs[4 * D_];
  __shared__ f32x4 red[256][5];
  const int t = threadIdx.x;
  const int row0 = blockIdx.x * 4;
  ((float2*)xs)[t] = ((const float2*)(x + row0 * D_))[t];
  __syncthreads();
  const int combo = t & 63;
  const int e4 = (combo & 31) * 4;
  const int half = combo >> 5;
  const int kq = t >> 6;
  const float* w1p = w1 + (half * D_ + kq * 32) * D_ + e4;
  const float* xq = xs + kq * 32;
  f32x4 acc[4] = {};
  #pragma unroll 8
  for (int k = 0; k < 32; ++k) {
    float4 wv = *(const float4*)(w1p + k * D_);
    #pragma unroll
    for (int r = 0; r < 4; ++r) {
      float xv = xq[r * D_ + k];
      acc[r][0] += xv * wv.x; acc[r][1] += xv * wv.y;
      acc[r][2] += xv * wv.z; acc[r][3] += xv * wv.w;
    }
  }
  #pragma unroll
  for (int r = 0; r < 4; ++r) red[t][r] = acc[r];
  __syncthreads();
  const int r = t >> 6;
  const int c2 = t & 63;
  f32x4 s = red[c2][r];
  #pragma unroll
  for (int q = 1; q < 4; ++q) {
    f32x4 v = red[c2 + 64 * q][r];
    s[0] += v[0]; s[1] += v[1]; s[2] += v[2]; s[3] += v[3];
  }
  const int fe4 = (c2 & 31) * 4;
  const int row = row0 + r;
  if ((c2 >> 5) == 0) {
    float4 bv = *(const float4*)(b1 + fe4);
    s[0] += bv.x; s[1] += bv.y; s[2] += bv.z; s[3] += bv.w;
    *(f32x4*)(Aq + row * D_ + fe4) = s;
  } else {
    *(f32x4*)(Cq + row * D_ + fe4) = s;
  }
}

// Edge v5: structure of r4 (64KB bf16 LDS, 2 blocks/CU, dbuf prefetch), but
// ALL hot f32->bf16 conversions via v_cvt_pk_bf16_f32 (1 instr / 2 elems).
// r8 counters: VALUBusy 75%, MfmaUtil 8.7% -> VALU-bound on SW bf16-rounding.
// MFMA A layout: row=lane&15 (=j), k=8*(lane>>4)+e. D: col=lane&15 (=h),
// row=(lane>>4)*4+reg (verified, absmax 3.9e-3).
__global__ __launch_bounds__(512, 4)
void edge_kernel(const float* __restrict__ Aq, const float* __restrict__ Cq,
                 const float* __restrict__ w2, const float* __restrict__ b2,
                 float* __restrict__ out) {
  __shared__ short cbf[256 * D_];        // 64 KB
  const int t = threadIdx.x;
  const int lane = t & 63;
  const int wid = t >> 6;                // 0..7
  const int b  = blockIdx.x >> 7;
  const int jh = (blockIdx.x >> 6) & 1;  // j half
  const int ig = blockIdx.x & 63;
  const int i = ig * 8 + wid;

  // ---- stage C[b][jh*256 .. +255][:] -> bf16 LDS via cvt_pk (4096 units)
  {
    const float* cb = Cq + (b * S_ + jh * 256) * D_;
    #pragma unroll
    for (int it = 0; it < 8; ++it) {
      int p = t + it * 512;
      int row = p >> 4;
      int u = p & 15;
      const float* src = cb + row * D_ + u * 8;
      float4 v0 = *(const float4*)(src);
      float4 v1 = *(const float4*)(src + 4);
      u32x4 w;
      w[0] = cvt_pk_bf16(v0.x, v0.y);
      w[1] = cvt_pk_bf16(v0.z, v0.w);
      w[2] = cvt_pk_bf16(v1.x, v1.y);
      w[3] = cvt_pk_bf16(v1.z, v1.w);
      *(u32x4*)(cbf + row * D_ + (u ^ (row & 7)) * 8) = w;
    }
  }

  const int jcol = lane & 15;            // j within tile == output h
  const int lgrp = lane >> 4;            // k-group
  const int sw = jcol & 7;

  // a registers as packed f32x2 (b1 folded): d = ch*32 + lgrp*8 + 2p (+0/1)
  f32x2 apk[4][4];
  {
    const float* Ai = Aq + (b * S_ + i) * D_ + lgrp * 8;
    #pragma unroll
    for (int ch = 0; ch < 4; ++ch) {
      float4 v0 = *(const float4*)(Ai + ch * 32);
      float4 v1 = *(const float4*)(Ai + ch * 32 + 4);
      apk[ch][0][0] = v0.x; apk[ch][0][1] = v0.y;
      apk[ch][1][0] = v0.z; apk[ch][1][1] = v0.w;
      apk[ch][2][0] = v1.x; apk[ch][2][1] = v1.y;
      apk[ch][3][0] = v1.z; apk[ch][3][1] = v1.w;
    }
  }
  // w2 B-fragments (cold): lane holds col h=jcol, k = ch*32 + lgrp*8 + e
  bf16x8 w2f[4];
  #pragma unroll
  for (int ch = 0; ch < 4; ++ch) {
    #pragma unroll
    for (int e = 0; e < 8; ++e) {
      float wv = (jcol < H_) ? w2[(ch * 32 + lgrp * 8 + e) * H_ + jcol] : 0.0f;
      w2f[ch][e] = f2bf(wv);
    }
  }
  const float b2v = (jcol < H_) ? b2[jcol] : 0.0f;
  float* outp = out + (((size_t)(b * H_ + (jcol & 7)) * S_ + i) * S_)
                + jh * 256 + lgrp * 4;

  __syncthreads();                       // only barrier

  u32x4 cva[4], cvb[4];                  // each dword = 2 bf16 C-elems
  auto LOADT = [&](u32x4 (&dst)[4], int jt) {
    const short* bp = cbf + (jt * 16 + jcol) * D_;
    #pragma unroll
    for (int ch = 0; ch < 4; ++ch)
      dst[ch] = *(const u32x4*)(bp + (((ch * 4 + lgrp) ^ sw) * 8));
  };
  auto COMPUTE = [&](u32x4 (&cv)[4], int jt) {
    f32x4 acc = {0.f, 0.f, 0.f, 0.f};
    #pragma unroll
    for (int ch = 0; ch < 4; ++ch) {
      u32x4 hfd;
      #pragma unroll
      for (int p = 0; p < 4; ++p) {
        unsigned int d = cv[ch][p];
        f32x2 v;
        v[0] = __builtin_bit_cast(float, d << 16);           // elem 2p
        v[1] = __builtin_bit_cast(float, d & 0xffff0000u);   // elem 2p+1
        v += apk[ch][p];                                     // v_pk_add_f32
        hfd[p] = cvt_pk_bf16(fmaxf(v[0], 0.f), fmaxf(v[1], 0.f));
      }
      bf16x8 hf = __builtin_bit_cast(bf16x8, hfd);
      acc = __builtin_amdgcn_mfma_f32_16x16x32_bf16(hf, w2f[ch], acc, 0, 0, 0);
    }
    if (jcol < H_) {
      float4 o;
      o.x = fsigmoid(acc[0] + b2v);
      o.y = fsigmoid(acc[1] + b2v);
      o.z = fsigmoid(acc[2] + b2v);
      o.w = fsigmoid(acc[3] + b2v);
      *(float4*)(outp + jt * 16) = o;
    }
  };

  LOADT(cva, 0);
  #pragma unroll 1
  for (int jt = 0; jt < 16; jt += 2) {
    LOADT(cvb, jt + 1);
    COMPUTE(cva, jt);
    LOADT(cva, (jt + 2) & 15);           // wrap harmless
    COMPUTE(cvb, jt + 1);
  }
}

extern "C" void kernel_launch(void* const* d_in, const int* in_sizes, int n_in,
                              void* d_out, int out_size, void* d_ws, size_t ws_size,
                              hipStream_t stream) {
  const float* x  = (const float*)d_in[0];
  const float* w1 = (const float*)d_in[1];
  const float* b1 = (const float*)d_in[2];
  const float* w2 = (const float*)d_in[3];
  const float* b2 = (const float*)d_in[4];
  float* out = (float*)d_out;
  float* Aq = (float*)d_ws;                 // 2048*128 f32 = 1 MB
  float* Cq = Aq + B_ * S_ * D_;            // +1 MB
  proj_kernel<<<(B_ * S_) / 4, 256, 0, stream>>>(x, w1, b1, Aq, Cq);
  edge_kernel<<<B_ * 2 * 64, 512, 0, stream>>>(Aq, Cq, w2, b2, out);
}